// Round 1
// baseline (1896.620 us; speedup 1.0000x reference)
//
#include <hip/hip_runtime.h>

typedef __attribute__((ext_vector_type(8))) short short8;
typedef __attribute__((ext_vector_type(4))) float floatx4;

#define B_   128
#define D_   512
#define V_   10000
#define T_   20
#define G4   2048
#define VPAD 10112
#define KPAD 10016
#define BD   (B_*D_)

__device__ __forceinline__ unsigned short f2b(float x){
  union { float f; unsigned u; } c; c.f = x;
  unsigned u = c.u;
  unsigned r = (u + 0x7fffu + ((u>>16)&1u)) >> 16;
  return (unsigned short)r;
}
__device__ __forceinline__ float sigm(float x){ return 1.0f/(1.0f+__expf(-x)); }

__global__ void k_convert(const float* __restrict__ src, unsigned short* __restrict__ dst, int n){
  int i = blockIdx.x*256 + threadIdx.x;
  if (i < n) dst[i] = f2b(src[i]);
}

__global__ void k_convert_pad(const float* __restrict__ src, unsigned short* __restrict__ dst,
                              int nsrc, int ntot){
  int i = blockIdx.x*256 + threadIdx.x;
  if (i < ntot) dst[i] = (i < nsrc) ? f2b(src[i]) : (unsigned short)0;
}

__global__ void k_zero(float* p, int n){
  int i = blockIdx.x*256 + threadIdx.x;
  if (i < n) p[i] = 0.f;
}

__global__ void k_addvec(const float* __restrict__ a, const float* __restrict__ b,
                         float* __restrict__ d, int n){
  int i = blockIdx.x*256 + threadIdx.x;
  if (i < n) d[i] = a[i] + b[i];
}

// bfold[g] = b_ih0[g] + b_hh0[g] + sum_v W_ih0[g][v]*b_enc[v]; biasA0 = b_ih0+b_hh0 (t=0 path)
__global__ void k_bias_fold(const float* __restrict__ Wih0, const float* __restrict__ b_enc,
                            const float* __restrict__ b_ih0, const float* __restrict__ b_hh0,
                            float* __restrict__ biasA0, float* __restrict__ bfold){
  __shared__ float red[256];
  int g = blockIdx.x;
  const float* row = Wih0 + (long)g*V_;
  float s = 0.f;
  for (int v = threadIdx.x; v < V_; v += 256) s += row[v]*b_enc[v];
  red[threadIdx.x] = s; __syncthreads();
  for (int w = 128; w >= 1; w >>= 1){
    if (threadIdx.x < w) red[threadIdx.x] += red[threadIdx.x+w];
    __syncthreads();
  }
  if (threadIdx.x == 0){
    float ba = b_ih0[g] + b_hh0[g];
    biasA0[g] = ba;
    bfold[g]  = ba + red[0];
  }
}

// M = W_ih0 (2048x10000, fp32, inline->bf16) @ Wenc_b (Vpad x 512 bf16), output bf16 (2048x512)
__global__ __launch_bounds__(256) void k_fold_gemm(const float* __restrict__ A,
                 const unsigned short* __restrict__ Bw,
                 unsigned short* __restrict__ Mout){
  __shared__ short At[64*40];
  __shared__ short Bt[64*40];
  int tid = threadIdx.x;
  int bn = blockIdx.x & 7, bm = blockIdx.x >> 3;
  int m0 = bm*64, n0 = bn*64;
  int lane = tid & 63, wave = tid >> 6;
  int l15 = lane & 15, quad = lane >> 4;
  int wm = (wave>>1)*32, wn = (wave&1)*32;
  floatx4 acc[2][2];
  #pragma unroll
  for (int i=0;i<2;i++)
    #pragma unroll
    for (int j=0;j<2;j++){ floatx4 z = {0.f,0.f,0.f,0.f}; acc[i][j] = z; }
  int arow = tid >> 2, ako = (tid&3)*8;
  int bkr  = tid >> 3, bdn = (tid&7)*8;
  for (int k0 = 0; k0 < KPAD; k0 += 32){
    {
      const float* src = A + (long)(m0+arow)*V_ + k0 + ako;
      short8 v;
      #pragma unroll
      for (int i=0;i<8;i++){
        int kidx = k0 + ako + i;
        float x = (kidx < V_) ? src[i] : 0.f;
        v[i] = (short)f2b(x);
      }
      *(short8*)(&At[arow*40 + ako]) = v;
    }
    {
      short8 v = *(const short8*)(Bw + (long)(k0+bkr)*D_ + n0 + bdn);
      #pragma unroll
      for (int i=0;i<8;i++) Bt[(bdn+i)*40 + bkr] = v[i];   // transpose to [n][k]
    }
    __syncthreads();
    short8 a0 = *(const short8*)(&At[(wm      + l15)*40 + quad*8]);
    short8 a1 = *(const short8*)(&At[(wm + 16 + l15)*40 + quad*8]);
    short8 b0 = *(const short8*)(&Bt[(wn      + l15)*40 + quad*8]);
    short8 b1 = *(const short8*)(&Bt[(wn + 16 + l15)*40 + quad*8]);
    acc[0][0] = __builtin_amdgcn_mfma_f32_16x16x32_bf16(a0,b0,acc[0][0],0,0,0);
    acc[0][1] = __builtin_amdgcn_mfma_f32_16x16x32_bf16(a0,b1,acc[0][1],0,0,0);
    acc[1][0] = __builtin_amdgcn_mfma_f32_16x16x32_bf16(a1,b0,acc[1][0],0,0,0);
    acc[1][1] = __builtin_amdgcn_mfma_f32_16x16x32_bf16(a1,b1,acc[1][1],0,0,0);
    __syncthreads();
  }
  #pragma unroll
  for (int mi=0;mi<2;mi++)
    #pragma unroll
    for (int ni=0;ni<2;ni++)
      #pragma unroll
      for (int r=0;r<4;r++){
        int g = m0 + wm + mi*16 + quad*4 + r;
        int d = n0 + wn + ni*16 + l15;
        Mout[(long)g*D_ + d] = f2b(acc[mi][ni][r]);
      }
}

// Fused LSTM layer step: gates(128x2048) = ha@WA^T + hb@WB^T + bias, then pointwise.
// Block covers hidden cols [j0, j0+16) across all 4 gates; wave g handles gate g.
__global__ __launch_bounds__(256) void k_lstm(
    const unsigned short* __restrict__ ha, const unsigned short* __restrict__ WA,
    const unsigned short* __restrict__ hb, const unsigned short* __restrict__ WB,
    const float* __restrict__ bias, float* __restrict__ c,
    unsigned short* __restrict__ hout)
{
  __shared__ short smem[27648];          // 55296 B
  short* Aa = smem;                      // [128][72]
  short* Ab = smem + 128*72;             // [128][72]
  short* Ba = smem + 2*128*72;           // [64][72]
  short* Bb = smem + 2*128*72 + 64*72;   // [64][72]
  int tid = threadIdx.x;
  int j0 = blockIdx.x * 16;
  int lane = tid & 63, wave = tid >> 6;
  int l15 = lane & 15, quad = lane >> 4;
  bool fA = (ha != nullptr), fB = (hb != nullptr);
  floatx4 acc[8];
  #pragma unroll
  for (int i=0;i<8;i++){ floatx4 z = {0.f,0.f,0.f,0.f}; acc[i] = z; }

  for (int k0 = 0; k0 < 512; k0 += 64){
    #pragma unroll
    for (int i=0;i<4;i++){
      int cc = tid + 256*i; int row = cc >> 3; int ko = (cc&7)*8;
      if (fA) *(short8*)(&Aa[row*72+ko]) = *(const short8*)(ha + row*512 + k0 + ko);
      if (fB) *(short8*)(&Ab[row*72+ko]) = *(const short8*)(hb + row*512 + k0 + ko);
    }
    #pragma unroll
    for (int i=0;i<2;i++){
      int cc = tid + 256*i; int row = cc >> 3; int ko = (cc&7)*8;
      int g = (row>>4)*512 + j0 + (row&15);
      if (fA) *(short8*)(&Ba[row*72+ko]) = *(const short8*)(WA + (long)g*512 + k0 + ko);
      if (fB) *(short8*)(&Bb[row*72+ko]) = *(const short8*)(WB + (long)g*512 + k0 + ko);
    }
    __syncthreads();
    #pragma unroll
    for (int kk=0; kk<2; kk++){
      if (fA){
        short8 b = *(const short8*)(&Ba[(wave*16 + l15)*72 + kk*32 + quad*8]);
        #pragma unroll
        for (int mt=0; mt<8; mt++){
          short8 a = *(const short8*)(&Aa[(mt*16 + l15)*72 + kk*32 + quad*8]);
          acc[mt] = __builtin_amdgcn_mfma_f32_16x16x32_bf16(a,b,acc[mt],0,0,0);
        }
      }
      if (fB){
        short8 b = *(const short8*)(&Bb[(wave*16 + l15)*72 + kk*32 + quad*8]);
        #pragma unroll
        for (int mt=0; mt<8; mt++){
          short8 a = *(const short8*)(&Ab[(mt*16 + l15)*72 + kk*32 + quad*8]);
          acc[mt] = __builtin_amdgcn_mfma_f32_16x16x32_bf16(a,b,acc[mt],0,0,0);
        }
      }
    }
    __syncthreads();
  }
  // exchange gates through LDS: ex[gate][b][jj]
  float* ex = (float*)smem;
  #pragma unroll
  for (int mt=0; mt<8; mt++)
    #pragma unroll
    for (int r=0;r<4;r++)
      ex[wave*2048 + (mt*16 + quad*4 + r)*16 + l15] = acc[mt][r];
  __syncthreads();
  int jj = tid & 15;
  int brow0 = tid >> 4;
  int j = j0 + jj;
  float bi = bias[j], bf = bias[512+j], bg = bias[1024+j], bo = bias[1536+j];
  #pragma unroll
  for (int i=0;i<8;i++){
    int b = brow0 + 16*i;
    float gi = ex[0*2048 + b*16 + jj] + bi;
    float gf = ex[1*2048 + b*16 + jj] + bf;
    float gg = ex[2*2048 + b*16 + jj] + bg;
    float go = ex[3*2048 + b*16 + jj] + bo;
    float ig = sigm(gi), fg = sigm(gf), gt = tanhf(gg), og = sigm(go);
    float cold = c[b*512 + j];
    float cn = fg*cold + ig*gt;
    c[b*512 + j] = cn;
    hout[b*512 + j] = f2b(og*tanhf(cn));
  }
}

// Out = Hs (2560x512 bf16) @ Wenc_b^T (+b_enc) -> fp32 (2560x10000)
__global__ __launch_bounds__(256) void k_out_gemm(
    const unsigned short* __restrict__ Ah,
    const unsigned short* __restrict__ Bw,
    const float* __restrict__ b_enc, float* __restrict__ out)
{
  __shared__ short At[128*40];
  __shared__ short Bt[128*40];
  int tid = threadIdx.x;
  int bm = blockIdx.x % 20, bn = blockIdx.x / 20;
  int m0 = bm*128, n0 = bn*128;
  int lane = tid&63, wave = tid>>6, l15 = lane&15, quad = lane>>4;
  int wm = (wave>>1)*64, wn = (wave&1)*64;
  floatx4 acc[4][4];
  #pragma unroll
  for (int i=0;i<4;i++)
    #pragma unroll
    for(int j=0;j<4;j++){ floatx4 z = {0.f,0.f,0.f,0.f}; acc[i][j] = z; }
  for (int k0=0;k0<512;k0+=32){
    #pragma unroll
    for (int i=0;i<2;i++){
      int cc = tid + 256*i; int row = cc>>2; int ko=(cc&3)*8;
      *(short8*)(&At[row*40+ko]) = *(const short8*)(Ah + (long)(m0+row)*512 + k0+ko);
      *(short8*)(&Bt[row*40+ko]) = *(const short8*)(Bw + (long)(n0+row)*512 + k0+ko);
    }
    __syncthreads();
    short8 af[4], bf[4];
    #pragma unroll
    for (int i=0;i<4;i++){
      af[i] = *(const short8*)(&At[(wm + i*16 + l15)*40 + quad*8]);
      bf[i] = *(const short8*)(&Bt[(wn + i*16 + l15)*40 + quad*8]);
    }
    #pragma unroll
    for (int mi=0;mi<4;mi++)
      #pragma unroll
      for (int ni=0;ni<4;ni++)
        acc[mi][ni] = __builtin_amdgcn_mfma_f32_16x16x32_bf16(af[mi],bf[ni],acc[mi][ni],0,0,0);
    __syncthreads();
  }
  #pragma unroll
  for (int mi=0;mi<4;mi++)
    #pragma unroll
    for (int ni=0;ni<4;ni++){
      int n = n0 + wn + ni*16 + l15;
      if (n < V_){
        float be = b_enc[n];
        #pragma unroll
        for (int r=0;r<4;r++){
          int m = m0 + wm + mi*16 + quad*4 + r;
          out[(long)m*V_ + n] = acc[mi][ni][r] + be;
        }
      }
    }
}

extern "C" void kernel_launch(void* const* d_in, const int* in_sizes, int n_in,
                              void* d_out, int out_size, void* d_ws, size_t ws_size,
                              hipStream_t stream){
  const float* input_ = (const float*)d_in[0];
  const float* W_ih0  = (const float*)d_in[1];
  const float* W_hh0  = (const float*)d_in[2];
  const float* b_ih0  = (const float*)d_in[3];
  const float* b_hh0  = (const float*)d_in[4];
  const float* W_ih1  = (const float*)d_in[5];
  const float* W_hh1  = (const float*)d_in[6];
  const float* b_ih1  = (const float*)d_in[7];
  const float* b_hh1  = (const float*)d_in[8];
  const float* W_enc  = (const float*)d_in[9];
  const float* b_enc  = (const float*)d_in[10];
  float* out = (float*)d_out;

  char* ws = (char*)d_ws;
  size_t off = 0;
  auto alloc = [&](size_t bytes){ void* p = ws + off; off += (bytes + 255) & ~255ull; return p; };
  unsigned short* Wenc_b  = (unsigned short*)alloc((size_t)VPAD*512*2);
  unsigned short* Mfold_b = (unsigned short*)alloc((size_t)G4*512*2);
  unsigned short* Whh0_b  = (unsigned short*)alloc((size_t)G4*512*2);
  unsigned short* Wih1_b  = (unsigned short*)alloc((size_t)G4*512*2);
  unsigned short* Whh1_b  = (unsigned short*)alloc((size_t)G4*512*2);
  unsigned short* Hs_b    = (unsigned short*)alloc((size_t)T_*BD*2);
  unsigned short* h0b0    = (unsigned short*)alloc((size_t)BD*2);
  unsigned short* h0b1    = (unsigned short*)alloc((size_t)BD*2);
  float* c0     = (float*)alloc((size_t)BD*4);
  float* c1     = (float*)alloc((size_t)BD*4);
  float* biasA0 = (float*)alloc(2048*4);
  float* bfold  = (float*)alloc(2048*4);
  float* bias1  = (float*)alloc(2048*4);
  unsigned short* h0b[2] = {h0b0, h0b1};

  k_convert_pad<<<(VPAD*512+255)/256, 256, 0, stream>>>(W_enc, Wenc_b, V_*512, VPAD*512);
  k_convert<<<(G4*512+255)/256, 256, 0, stream>>>(W_hh0, Whh0_b, G4*512);
  k_convert<<<(G4*512+255)/256, 256, 0, stream>>>(W_ih1, Wih1_b, G4*512);
  k_convert<<<(G4*512+255)/256, 256, 0, stream>>>(W_hh1, Whh1_b, G4*512);
  k_convert<<<(BD+255)/256, 256, 0, stream>>>(input_, h0b[0], BD);
  k_zero<<<(BD+255)/256, 256, 0, stream>>>(c0, BD);
  k_zero<<<(BD+255)/256, 256, 0, stream>>>(c1, BD);
  k_addvec<<<8, 256, 0, stream>>>(b_ih1, b_hh1, bias1, 2048);
  k_bias_fold<<<2048, 256, 0, stream>>>(W_ih0, b_enc, b_ih0, b_hh0, biasA0, bfold);
  k_fold_gemm<<<256, 256, 0, stream>>>(W_ih0, Wenc_b, Mfold_b);

  for (int t = 0; t < T_; t++){
    const unsigned short* h1p = (t == 0) ? nullptr : (Hs_b + (size_t)(t-1)*BD);
    k_lstm<<<32, 256, 0, stream>>>(h1p, Mfold_b, h0b[t&1], Whh0_b,
                                   (t==0) ? biasA0 : bfold, c0, h0b[(t+1)&1]);
    k_lstm<<<32, 256, 0, stream>>>(h0b[(t+1)&1], Wih1_b, h1p, Whh1_b,
                                   bias1, c1, Hs_b + (size_t)t*BD);
  }
  k_out_gemm<<<20*79, 256, 0, stream>>>(Hs_b, Wenc_b, b_enc, out);
}

// Round 2
// 1085.763 us; speedup vs baseline: 1.7468x; 1.7468x over previous
//
#include <hip/hip_runtime.h>

typedef __attribute__((ext_vector_type(8))) short short8;
typedef __attribute__((ext_vector_type(4))) short short4v;
typedef __attribute__((ext_vector_type(4))) float floatx4;

#define B_   128
#define D_   512
#define V_   10000
#define T_   20
#define G4   2048
#define VPAD 10112
#define KP2  10240
#define BD   (B_*D_)

__device__ __forceinline__ unsigned short f2b(float x){
  union { float f; unsigned u; } c; c.f = x;
  unsigned u = c.u;
  unsigned r = (u + 0x7fffu + ((u>>16)&1u)) >> 16;
  return (unsigned short)r;
}
__device__ __forceinline__ float sigm(float x){ return 1.0f/(1.0f+__expf(-x)); }

__global__ void k_convert(const float* __restrict__ src, unsigned short* __restrict__ dst, int n){
  int i = blockIdx.x*256 + threadIdx.x;
  if (i < n) dst[i] = f2b(src[i]);
}

__global__ void k_zero(float* p, int n){
  int i = blockIdx.x*256 + threadIdx.x;
  if (i < n) p[i] = 0.f;
}

__global__ void k_addvec(const float* __restrict__ a, const float* __restrict__ b,
                         float* __restrict__ d, int n){
  int i = blockIdx.x*256 + threadIdx.x;
  if (i < n) d[i] = a[i] + b[i];
}

// Transpose+convert W_enc (10000x512 fp32) into:
//   Wenc_b  [VPAD][512]  bf16 (row-major, for out_gemm; rows >=10000 zero)
//   WencT_b [512][KP2]   bf16 (K-major, for fold_gemm; cols >=10000 zero)
__global__ __launch_bounds__(256) void k_trans(const float* __restrict__ Wenc,
    unsigned short* __restrict__ Wenc_b, unsigned short* __restrict__ WencT){
  __shared__ short T[64*72];
  int tid = threadIdx.x;
  int v0 = blockIdx.x * 64;      // 160 tiles over KP2
  int d0 = blockIdx.y * 64;      // 8 tiles over 512
  #pragma unroll
  for (int i=0;i<4;i++){
    int s = tid + 256*i;          // 1024 slots: 64 rows x 16 float4
    int row = s >> 4, fq = s & 15;
    int v = v0 + row, d = d0 + fq*4;
    float4 f = {0.f,0.f,0.f,0.f};
    if (v < V_) f = *(const float4*)(Wenc + (long)v*D_ + d);
    short4v h; h[0]=(short)f2b(f.x); h[1]=(short)f2b(f.y); h[2]=(short)f2b(f.z); h[3]=(short)f2b(f.w);
    *(short4v*)(&T[row*72 + fq*4]) = h;
    if (v < VPAD) *(short4v*)(Wenc_b + (long)v*D_ + d) = h;
  }
  __syncthreads();
  #pragma unroll
  for (int i=0;i<2;i++){
    int s = tid + 256*i;          // 512 slots: 64 d-rows x 8 short8
    int drow = s >> 3, oct = s & 7;
    short8 v8;
    #pragma unroll
    for (int j=0;j<8;j++) v8[j] = T[(oct*8+j)*72 + drow];
    *(short8*)(WencT + (long)(d0+drow)*KP2 + v0 + oct*8) = v8;
  }
}

// bfold[g] = b_ih0[g]+b_hh0[g] + sum_v W_ih0[g][v]*b_enc[v]; biasA0 = b_ih0+b_hh0
__global__ void k_bias_fold(const float* __restrict__ Wih0, const float* __restrict__ b_enc,
                            const float* __restrict__ b_ih0, const float* __restrict__ b_hh0,
                            float* __restrict__ biasA0, float* __restrict__ bfold){
  __shared__ float red[256];
  int g = blockIdx.x;
  const float* row = Wih0 + (long)g*V_;
  float s = 0.f;
  for (int v = threadIdx.x; v < V_; v += 256) s += row[v]*b_enc[v];
  red[threadIdx.x] = s; __syncthreads();
  for (int w = 128; w >= 1; w >>= 1){
    if (threadIdx.x < w) red[threadIdx.x] += red[threadIdx.x+w];
    __syncthreads();
  }
  if (threadIdx.x == 0){
    float ba = b_ih0[g] + b_hh0[g];
    biasA0[g] = ba;
    bfold[g]  = ba + red[0];
  }
}

// Mf32 (2048x512 fp32, atomically accumulated) += W_ih0 (fp32, inline bf16) @ WencT^T
// Grid: 8 ksplits x 16 m-blocks x 4 n-blocks = 512 blocks; 128x128 tile, K=1280 each.
__global__ __launch_bounds__(256) void k_fold_gemm(const float* __restrict__ A,
                 const unsigned short* __restrict__ BT, float* __restrict__ Mf32){
  __shared__ short At[128*40];
  __shared__ short Bt[128*40];
  int tid = threadIdx.x;
  int b = blockIdx.x;
  int ks = b >> 6, mn = b & 63;
  int bm = mn >> 2, bn = mn & 3;
  int m0 = bm*128, n0 = bn*128, kb = ks*1280;
  int lane = tid&63, wave = tid>>6, l15 = lane&15, quad = lane>>4;
  int wm = (wave>>1)*64, wn = (wave&1)*64;
  floatx4 acc[4][4];
  #pragma unroll
  for (int i=0;i<4;i++)
    #pragma unroll
    for(int j=0;j<4;j++){ floatx4 z = {0.f,0.f,0.f,0.f}; acc[i][j] = z; }
  for (int it = 0; it < 40; it++){
    int k0 = kb + it*32;
    #pragma unroll
    for (int i=0;i<2;i++){
      int slot = tid + 256*i;           // 512 slots: 128 rows x 4 octs
      int row = slot >> 2, oct = slot & 3;
      const float* src = A + (long)(m0+row)*V_ + k0 + oct*8;
      short8 v;
      if (k0 + 32 <= V_){
        float4 f0 = *(const float4*)src;
        float4 f1 = *(const float4*)(src+4);
        v[0]=(short)f2b(f0.x); v[1]=(short)f2b(f0.y); v[2]=(short)f2b(f0.z); v[3]=(short)f2b(f0.w);
        v[4]=(short)f2b(f1.x); v[5]=(short)f2b(f1.y); v[6]=(short)f2b(f1.z); v[7]=(short)f2b(f1.w);
      } else {
        #pragma unroll
        for (int j=0;j<8;j++){
          int kk = k0 + oct*8 + j;
          float x = (kk < V_) ? src[j] : 0.f;
          v[j] = (short)f2b(x);
        }
      }
      *(short8*)(&At[row*40 + oct*8]) = v;
    }
    #pragma unroll
    for (int i=0;i<2;i++){
      int slot = tid + 256*i;
      int row = slot >> 2, oct = slot & 3;
      *(short8*)(&Bt[row*40 + oct*8]) = *(const short8*)(BT + (long)(n0+row)*KP2 + k0 + oct*8);
    }
    __syncthreads();
    short8 af[4], bf[4];
    #pragma unroll
    for (int i=0;i<4;i++){
      af[i] = *(const short8*)(&At[(wm + i*16 + l15)*40 + quad*8]);
      bf[i] = *(const short8*)(&Bt[(wn + i*16 + l15)*40 + quad*8]);
    }
    #pragma unroll
    for (int mi=0;mi<4;mi++)
      #pragma unroll
      for (int ni=0;ni<4;ni++)
        acc[mi][ni] = __builtin_amdgcn_mfma_f32_16x16x32_bf16(af[mi],bf[ni],acc[mi][ni],0,0,0);
    __syncthreads();
  }
  #pragma unroll
  for (int mi=0;mi<4;mi++)
    #pragma unroll
    for (int ni=0;ni<4;ni++){
      int n = n0 + wn + ni*16 + l15;
      #pragma unroll
      for (int r=0;r<4;r++){
        int m = m0 + wm + mi*16 + quad*4 + r;
        atomicAdd(&Mf32[(long)m*D_ + n], acc[mi][ni][r]);
      }
    }
}

// Fused LSTM step (one layer): gates(128x2048) = ha@WA^T + hb@WB^T + bias, pointwise.
// Grid 128: 4 batch-splits x 32 col-groups of 16. Wave = gate.
__global__ __launch_bounds__(256) void k_lstm(
    const unsigned short* __restrict__ ha, const unsigned short* __restrict__ WA,
    const unsigned short* __restrict__ hb, const unsigned short* __restrict__ WB,
    const float* __restrict__ bias, float* __restrict__ c,
    unsigned short* __restrict__ hout)
{
  __shared__ short smem[13824];          // 27648 B
  short* Aa = smem;                      // [32][72]
  short* Ab = smem + 32*72;              // [32][72]
  short* Ba = smem + 2*32*72;            // [64][72]
  short* Bb = smem + 2*32*72 + 64*72;    // [64][72]
  int tid = threadIdx.x;
  int bs = blockIdx.x & 3, jg = blockIdx.x >> 2;
  int br0 = bs*32, j0 = jg*16;
  int lane = tid & 63, wave = tid >> 6;
  int l15 = lane & 15, quad = lane >> 4;
  bool fA = (ha != nullptr), fB = (hb != nullptr);
  floatx4 acc[2];
  #pragma unroll
  for (int i=0;i<2;i++){ floatx4 z = {0.f,0.f,0.f,0.f}; acc[i] = z; }

  for (int k0 = 0; k0 < 512; k0 += 64){
    {
      int row = tid >> 3, oct = tid & 7;          // 256 slots: 32 rows x 8 octs
      if (fA) *(short8*)(&Aa[row*72+oct*8]) = *(const short8*)(ha + (br0+row)*512 + k0 + oct*8);
      if (fB) *(short8*)(&Ab[row*72+oct*8]) = *(const short8*)(hb + (br0+row)*512 + k0 + oct*8);
    }
    #pragma unroll
    for (int i=0;i<2;i++){
      int slot = tid + 256*i;                     // 512 slots: 64 rows x 8 octs
      int row = slot >> 3, oct = slot & 7;
      int g = (row>>4)*512 + j0 + (row&15);
      if (fA) *(short8*)(&Ba[row*72+oct*8]) = *(const short8*)(WA + (long)g*512 + k0 + oct*8);
      if (fB) *(short8*)(&Bb[row*72+oct*8]) = *(const short8*)(WB + (long)g*512 + k0 + oct*8);
    }
    __syncthreads();
    #pragma unroll
    for (int kk=0; kk<2; kk++){
      if (fA){
        short8 b = *(const short8*)(&Ba[(wave*16 + l15)*72 + kk*32 + quad*8]);
        #pragma unroll
        for (int mt=0; mt<2; mt++){
          short8 a = *(const short8*)(&Aa[(mt*16 + l15)*72 + kk*32 + quad*8]);
          acc[mt] = __builtin_amdgcn_mfma_f32_16x16x32_bf16(a,b,acc[mt],0,0,0);
        }
      }
      if (fB){
        short8 b = *(const short8*)(&Bb[(wave*16 + l15)*72 + kk*32 + quad*8]);
        #pragma unroll
        for (int mt=0; mt<2; mt++){
          short8 a = *(const short8*)(&Ab[(mt*16 + l15)*72 + kk*32 + quad*8]);
          acc[mt] = __builtin_amdgcn_mfma_f32_16x16x32_bf16(a,b,acc[mt],0,0,0);
        }
      }
    }
    __syncthreads();
  }
  // exchange gates through LDS: ex[gate][b_local][jj]
  float* ex = (float*)smem;    // 4*32*16 floats = 8 KB
  #pragma unroll
  for (int mt=0; mt<2; mt++)
    #pragma unroll
    for (int r=0;r<4;r++)
      ex[wave*512 + (mt*16 + quad*4 + r)*16 + l15] = acc[mt][r];
  __syncthreads();
  #pragma unroll
  for (int i=0;i<2;i++){
    int e = tid + 256*i;                 // 512 elems: 32 b x 16 j
    int bl = e >> 4, jj = e & 15;
    int b = br0 + bl, j = j0 + jj;
    float gi = ex[0*512 + bl*16 + jj] + bias[j];
    float gf = ex[1*512 + bl*16 + jj] + bias[512+j];
    float gg = ex[2*512 + bl*16 + jj] + bias[1024+j];
    float go = ex[3*512 + bl*16 + jj] + bias[1536+j];
    float ig = sigm(gi), fg = sigm(gf), gt = tanhf(gg), og = sigm(go);
    float cold = c[b*512 + j];
    float cn = fg*cold + ig*gt;
    c[b*512 + j] = cn;
    hout[b*512 + j] = f2b(og*tanhf(cn));
  }
}

// Out = Hs (2560x512 bf16) @ Wenc_b^T (+b_enc) -> fp32 (2560x10000)
__global__ __launch_bounds__(256) void k_out_gemm(
    const unsigned short* __restrict__ Ah,
    const unsigned short* __restrict__ Bw,
    const float* __restrict__ b_enc, float* __restrict__ out)
{
  __shared__ short At[128*40];
  __shared__ short Bt[128*40];
  int tid = threadIdx.x;
  int bm = blockIdx.x % 20, bn = blockIdx.x / 20;
  int m0 = bm*128, n0 = bn*128;
  int lane = tid&63, wave = tid>>6, l15 = lane&15, quad = lane>>4;
  int wm = (wave>>1)*64, wn = (wave&1)*64;
  floatx4 acc[4][4];
  #pragma unroll
  for (int i=0;i<4;i++)
    #pragma unroll
    for(int j=0;j<4;j++){ floatx4 z = {0.f,0.f,0.f,0.f}; acc[i][j] = z; }
  for (int k0=0;k0<512;k0+=32){
    #pragma unroll
    for (int i=0;i<2;i++){
      int cc = tid + 256*i; int row = cc>>2; int ko=(cc&3)*8;
      *(short8*)(&At[row*40+ko]) = *(const short8*)(Ah + (long)(m0+row)*512 + k0+ko);
      *(short8*)(&Bt[row*40+ko]) = *(const short8*)(Bw + (long)(n0+row)*512 + k0+ko);
    }
    __syncthreads();
    short8 af[4], bf[4];
    #pragma unroll
    for (int i=0;i<4;i++){
      af[i] = *(const short8*)(&At[(wm + i*16 + l15)*40 + quad*8]);
      bf[i] = *(const short8*)(&Bt[(wn + i*16 + l15)*40 + quad*8]);
    }
    #pragma unroll
    for (int mi=0;mi<4;mi++)
      #pragma unroll
      for (int ni=0;ni<4;ni++)
        acc[mi][ni] = __builtin_amdgcn_mfma_f32_16x16x32_bf16(af[mi],bf[ni],acc[mi][ni],0,0,0);
    __syncthreads();
  }
  #pragma unroll
  for (int mi=0;mi<4;mi++)
    #pragma unroll
    for (int ni=0;ni<4;ni++){
      int n = n0 + wn + ni*16 + l15;
      if (n < V_){
        float be = b_enc[n];
        #pragma unroll
        for (int r=0;r<4;r++){
          int m = m0 + wm + mi*16 + quad*4 + r;
          out[(long)m*V_ + n] = acc[mi][ni][r] + be;
        }
      }
    }
}

extern "C" void kernel_launch(void* const* d_in, const int* in_sizes, int n_in,
                              void* d_out, int out_size, void* d_ws, size_t ws_size,
                              hipStream_t stream){
  const float* input_ = (const float*)d_in[0];
  const float* W_ih0  = (const float*)d_in[1];
  const float* W_hh0  = (const float*)d_in[2];
  const float* b_ih0  = (const float*)d_in[3];
  const float* b_hh0  = (const float*)d_in[4];
  const float* W_ih1  = (const float*)d_in[5];
  const float* W_hh1  = (const float*)d_in[6];
  const float* b_ih1  = (const float*)d_in[7];
  const float* b_hh1  = (const float*)d_in[8];
  const float* W_enc  = (const float*)d_in[9];
  const float* b_enc  = (const float*)d_in[10];
  float* out = (float*)d_out;

  char* ws = (char*)d_ws;
  size_t off = 0;
  auto alloc = [&](size_t bytes){ void* p = ws + off; off += (bytes + 255) & ~255ull; return p; };
  unsigned short* Wenc_b  = (unsigned short*)alloc((size_t)VPAD*512*2);
  unsigned short* WencT_b = (unsigned short*)alloc((size_t)512*KP2*2);
  float*          Mf32    = (float*)alloc((size_t)G4*512*4);
  unsigned short* Mfold_b = (unsigned short*)alloc((size_t)G4*512*2);
  unsigned short* Whh0_b  = (unsigned short*)alloc((size_t)G4*512*2);
  unsigned short* Wih1_b  = (unsigned short*)alloc((size_t)G4*512*2);
  unsigned short* Whh1_b  = (unsigned short*)alloc((size_t)G4*512*2);
  unsigned short* Hs_b    = (unsigned short*)alloc((size_t)T_*BD*2);
  unsigned short* h0b0    = (unsigned short*)alloc((size_t)BD*2);
  unsigned short* h0b1    = (unsigned short*)alloc((size_t)BD*2);
  float* c0     = (float*)alloc((size_t)BD*4);
  float* c1     = (float*)alloc((size_t)BD*4);
  float* biasA0 = (float*)alloc(2048*4);
  float* bfold  = (float*)alloc(2048*4);
  float* bias1  = (float*)alloc(2048*4);
  unsigned short* h0b[2] = {h0b0, h0b1};

  k_trans<<<dim3(KP2/64, 512/64), 256, 0, stream>>>(W_enc, Wenc_b, WencT_b);
  k_convert<<<(G4*512+255)/256, 256, 0, stream>>>(W_hh0, Whh0_b, G4*512);
  k_convert<<<(G4*512+255)/256, 256, 0, stream>>>(W_ih1, Wih1_b, G4*512);
  k_convert<<<(G4*512+255)/256, 256, 0, stream>>>(W_hh1, Whh1_b, G4*512);
  k_convert<<<(BD+255)/256, 256, 0, stream>>>(input_, h0b[0], BD);
  k_zero<<<(BD+255)/256, 256, 0, stream>>>(c0, BD);
  k_zero<<<(BD+255)/256, 256, 0, stream>>>(c1, BD);
  k_zero<<<(G4*512+255)/256, 256, 0, stream>>>(Mf32, G4*512);
  k_addvec<<<8, 256, 0, stream>>>(b_ih1, b_hh1, bias1, 2048);
  k_bias_fold<<<2048, 256, 0, stream>>>(W_ih0, b_enc, b_ih0, b_hh0, biasA0, bfold);
  k_fold_gemm<<<512, 256, 0, stream>>>(W_ih0, WencT_b, Mf32);
  k_convert<<<(G4*512+255)/256, 256, 0, stream>>>(Mf32, Mfold_b, G4*512);

  for (int t = 0; t < T_; t++){
    const unsigned short* h1p = (t == 0) ? nullptr : (Hs_b + (size_t)(t-1)*BD);
    k_lstm<<<128, 256, 0, stream>>>(h1p, Mfold_b, h0b[t&1], Whh0_b,
                                    (t==0) ? biasA0 : bfold, c0, h0b[(t+1)&1]);
    k_lstm<<<128, 256, 0, stream>>>(h0b[(t+1)&1], Wih1_b, h1p, Whh1_b,
                                    bias1, c1, Hs_b + (size_t)t*BD);
  }
  k_out_gemm<<<20*79, 256, 0, stream>>>(Hs_b, Wenc_b, b_enc, out);
}